// Round 5
// baseline (94.848 us; speedup 1.0000x reference)
//
#include <hip/hip_runtime.h>

// out[b][s][d] = W[d][s] + bias[d]  for b in [0,4), s in [0,4096), d in [0,1024)
// ALL f32 (evidence: r3 f32-write read back finite; r4 bf16-read of inputs -> NaN
// => inputs are f32, output read as f32; matches reference's jnp.float32).
// W is [1024, 8192] row-major (row stride ML=8192 floats). x (input 0) unused:
// one_hot(arange(S)) @ W.T + b is a row-gather = transpose of W[:, :S] + bias.
//
// Write-BW-bound transpose: 64x64 LDS tile, coalesced float4 in/out,
// 4x batch broadcast from one LDS read.
// Roofline: 16 MiB read + 64 MiB write @ ~6.3 TB/s achievable ~= 13 us.
// Known: LDS scatter-write is 8-way bank-conflicted (bounded ~1-2 us);
// fix with swizzle ONLY after a passing baseline with counters.

#define S_DIM 4096
#define D_DIM 1024
#define ML    8192
#define BATCH 4
#define TILE  64
#define PITCH 68  // 64 + 4 pad: row = 272 B = 17*16 B -> float4-aligned rows

__global__ __launch_bounds__(256) void pos_emb_kernel(const float* __restrict__ W,
                                                      const float* __restrict__ bias,
                                                      float* __restrict__ out) {
    __shared__ float tile[TILE * PITCH];

    const int tid    = threadIdx.x;
    const int tile_s = blockIdx.x & 63;   // 64 s-tiles
    const int tile_d = blockIdx.x >> 6;   // 16 d-tiles
    const int s0     = tile_s * TILE;
    const int d0     = tile_d * TILE;

    // ---- Load phase: coalesced along s, scatter transposed into LDS ----
    // sv = float4 index along s (0..15), dr = d row (0..15), 4 passes over d
    const int sv = tid & 15;
    const int dr = tid >> 4;
    #pragma unroll
    for (int p = 0; p < 4; ++p) {
        const int d = dr + p * 16;
        const float4 v = *reinterpret_cast<const float4*>(
            &W[(size_t)(d0 + d) * ML + (size_t)s0 + sv * 4]);
        tile[(sv * 4 + 0) * PITCH + d] = v.x;
        tile[(sv * 4 + 1) * PITCH + d] = v.y;
        tile[(sv * 4 + 2) * PITCH + d] = v.z;
        tile[(sv * 4 + 3) * PITCH + d] = v.w;
    }

    // ---- Bias for write-phase d-slice (independent of LDS, overlaps latency) ----
    const int dv = tid & 15;   // float4 index along d (0..15)
    const int sr = tid >> 4;   // s row (0..15), 4 passes over s
    const float4 bvec = *reinterpret_cast<const float4*>(&bias[d0 + dv * 4]);

    __syncthreads();

    // ---- Write phase: b128 LDS read along d, coalesced float4 stores x4 batches ----
    #pragma unroll
    for (int p = 0; p < 4; ++p) {
        const int s = sr + p * 16;
        float4 v = *reinterpret_cast<const float4*>(&tile[s * PITCH + dv * 4]);
        v.x += bvec.x; v.y += bvec.y; v.z += bvec.z; v.w += bvec.w;
        const size_t o = (size_t)(s0 + s) * D_DIM + (size_t)d0 + dv * 4;
        #pragma unroll
        for (int b = 0; b < BATCH; ++b) {
            *reinterpret_cast<float4*>(&out[(size_t)b * S_DIM * D_DIM + o]) = v;
        }
    }
}

extern "C" void kernel_launch(void* const* d_in, const int* in_sizes, int n_in,
                              void* d_out, int out_size, void* d_ws, size_t ws_size,
                              hipStream_t stream) {
    // inputs: [0] x (unused, f32), [1] W [1024*8192] f32, [2] b [1024] f32
    const float* W = (const float*)d_in[1];
    const float* b = (const float*)d_in[2];
    float* out     = (float*)d_out;

    const int grid = (S_DIM / TILE) * (D_DIM / TILE);  // 64 * 16 = 1024
    pos_emb_kernel<<<dim3(grid), dim3(256), 0, stream>>>(W, b, out);
}